// Round 10
// baseline (54.926 us; speedup 1.0000x reference)
//
#include <hip/hip_runtime.h>
#include <hip/hip_bf16.h>

#define B_  16
#define S_  1024
#define D_  64

typedef __attribute__((ext_vector_type(8))) short bf16x8;
typedef __attribute__((ext_vector_type(4))) float f32x4;

__device__ __forceinline__ short f2bf(float f) {
    __hip_bfloat16 h = __float2bfloat16(f);   // RTNE; fuses to v_cvt_pk_bf16_f32
    return __builtin_bit_cast(short, h);
}

// bf16 MFMA flash attention, no K/V LDS staging (L2/L3-direct).
// Algebra: mx_t = max_b(t_m) >= every element -> |t_m-mx_t| = mx_t-t_m ->
// scores = QK/64 - t_m - g_m + const(b); softmax shift-invariant ->
// batch-max pass dropped.
// Block = (batch, 16-q tile), 256 thr = 4 waves; wave w owns k-strips
// {128t + 32w}; no barriers in main loop (s_p wave-private).
// NEW (R10): bias registers double-buffered across k-iterations — tile t+1's
// 32 HBM-cold bias loads issue during tile t's compute (~1200cy cover vs
// ~900cy latency). Named A/B buffers, manual 2x unroll (no runtime idx).
__global__ __launch_bounds__(256, 4) void attn_mfma_kernel(
    const float* __restrict__ Q, const float* __restrict__ K,
    const float* __restrict__ V, const float* __restrict__ t_m,
    const float* __restrict__ g_m, float* __restrict__ out)
{
    __shared__ __align__(16) char smem[17920];
    unsigned short (*s_p)[136] = (unsigned short (*)[136])smem;  // [16][136] bf16
    float* cmb = (float*)smem;            // overlay post-loop: [4][16][68] f32
    float* cml = (float*)(smem + 17408);  // overlay post-loop: [4][2][16]  f32

    const int bid = blockIdx.x;
    const int b   = bid & 15;
    const int g   = bid >> 4;                            // [0,64)
    const int qt  = (g < 32) ? (63 - g) : (g - 32);      // balance heavy+light
    const int qb  = qt << 4;
    const int tid = threadIdx.x;
    const int w   = tid >> 6;      // wave 0..3 -> k-strip
    const int ln  = tid & 63;
    const int lg  = ln >> 4;       // lane group 0..3
    const int lm  = ln & 15;       // 0..15

    const size_t kvb   = (size_t)(b * S_) * D_;
    const size_t biasb = (size_t)b * S_ * S_;
    const float* Kb = K + kvb;
    const float* Vb = V + kvb;
    const float* tmb = t_m + biasb + (size_t)(qb + 4 * lg) * S_ + lm;
    const float* gmb = g_m + biasb + (size_t)(qb + 4 * lg) * S_ + lm;

    // ---- persistent Q fragment: A[m=lm][d = 32ks + 8lg + j] ----
    bf16x8 qa[2];
    #pragma unroll
    for (int ks = 0; ks < 2; ++ks) {
        const float* qp = Q + ((size_t)(b * S_) + qb + lm) * D_ + 32 * ks + 8 * lg;
        const float4 x = *(const float4*)qp;
        const float4 y = *(const float4*)(qp + 4);
        bf16x8 f;
        f[0] = f2bf(x.x); f[1] = f2bf(x.y);
        f[2] = f2bf(x.z); f[3] = f2bf(x.w);
        f[4] = f2bf(y.x); f[5] = f2bf(y.y);
        f[6] = f2bf(y.z); f[7] = f2bf(y.w);
        qa[ks] = f;
    }

    float mrun[4] = {-1e30f, -1e30f, -1e30f, -1e30f};
    float lrun[4] = {0.f, 0.f, 0.f, 0.f};
    const f32x4 z4 = {0.f, 0.f, 0.f, 0.f};
    f32x4 oacc[4] = {z4, z4, z4, z4};

    // wave-private causal tile count: strips 128t + 32w that touch k <= qb+15
    const int ntw = ((qb + 15 - 32 * w) >> 7) + 1;   // <=0 when strip beyond diag

    float btA[2][4], bgA[2][4], btB[2][4], bgB[2][4];

#define LOADBIAS(KE, BT, BG)                                               \
    {                                                                      \
        _Pragma("unroll")                                                  \
        for (int nf = 0; nf < 2; ++nf) {                                   \
            _Pragma("unroll")                                              \
            for (int r = 0; r < 4; ++r) {                                  \
                const size_t off_ = (size_t)r * S_ + (KE) + 16 * nf;       \
                BT[nf][r] = tmb[off_];                                     \
                BG[nf][r] = gmb[off_];                                     \
            }                                                              \
        }                                                                  \
    }

#define BODY(T, BTC, BGC, BTN, BGN)                                        \
    {                                                                      \
        const int ke = ((T) << 7) + 32 * w;                                \
        /* K frags direct from L2: B[n=lm][d=32ks+8lg+j] */                \
        bf16x8 kf[2][2];                                                   \
        _Pragma("unroll")                                                  \
        for (int nf = 0; nf < 2; ++nf) {                                   \
            _Pragma("unroll")                                              \
            for (int ks = 0; ks < 2; ++ks) {                               \
                const float* kp = Kb + (size_t)(ke + 16 * nf + lm) * D_    \
                                + 32 * ks + 8 * lg;                        \
                const float4 x = *(const float4*)kp;                       \
                const float4 y = *(const float4*)(kp + 4);                 \
                bf16x8 f;                                                  \
                f[0] = f2bf(x.x); f[1] = f2bf(x.y);                        \
                f[2] = f2bf(x.z); f[3] = f2bf(x.w);                        \
                f[4] = f2bf(y.x); f[5] = f2bf(y.y);                        \
                f[6] = f2bf(y.z); f[7] = f2bf(y.w);                        \
                kf[nf][ks] = f;                                            \
            }                                                              \
        }                                                                  \
        /* prefetch NEXT tile's bias (HBM ~900cy hides under this tile) */ \
        if ((T) + 1 < ntw) LOADBIAS(ke + 128, BTN, BGN)                    \
        /* S = Q K^T (4 MFMA) */                                           \
        f32x4 sa[2] = {z4, z4};                                            \
        _Pragma("unroll")                                                  \
        for (int nf = 0; nf < 2; ++nf) {                                   \
            _Pragma("unroll")                                              \
            for (int ks = 0; ks < 2; ++ks)                                 \
                sa[nf] = __builtin_amdgcn_mfma_f32_16x16x32_bf16(          \
                    qa[ks], kf[nf][ks], sa[nf], 0, 0, 0);                  \
        }                                                                  \
        /* V prefetch (L2-hot; covered by softmax) */                      \
        float vf[4][8];                                                    \
        _Pragma("unroll")                                                  \
        for (int nd = 0; nd < 4; ++nd) {                                   \
            _Pragma("unroll")                                              \
            for (int j = 0; j < 8; ++j)                                    \
                vf[nd][j] = Vb[(size_t)(ke + 8 * lg + j) * D_ + 16 * nd + lm]; \
        }                                                                  \
        /* scores: QK/64 - t - g, causal mask */                           \
        float p[2][4], tmax[4];                                            \
        _Pragma("unroll")                                                  \
        for (int r = 0; r < 4; ++r) {                                      \
            const int qg = qb + 4 * lg + r;                                \
            float s0 = sa[0][r] * (1.f / 64.f) - BTC[0][r] - BGC[0][r];    \
            float s1 = sa[1][r] * (1.f / 64.f) - BTC[1][r] - BGC[1][r];    \
            if (ke + lm > qg)      s0 = -1e30f;                            \
            if (ke + 16 + lm > qg) s1 = -1e30f;                            \
            p[0][r] = s0;  p[1][r] = s1;                                   \
            tmax[r] = fmaxf(s0, s1);                                       \
        }                                                                  \
        _Pragma("unroll")                                                  \
        for (int off = 1; off < 16; off <<= 1) {                           \
            _Pragma("unroll")                                              \
            for (int r = 0; r < 4; ++r)                                    \
                tmax[r] = fmaxf(tmax[r], __shfl_xor(tmax[r], off, 64));    \
        }                                                                  \
        _Pragma("unroll")                                                  \
        for (int r = 0; r < 4; ++r) {                                      \
            const float mn = fmaxf(mrun[r], tmax[r]);                      \
            const float a  = __expf(mrun[r] - mn);                         \
            mrun[r] = mn;                                                  \
            const float p0 = __expf(p[0][r] - mn);                         \
            const float p1 = __expf(p[1][r] - mn);                         \
            p[0][r] = p0;  p[1][r] = p1;                                   \
            float rs = p0 + p1;                                            \
            _Pragma("unroll")                                              \
            for (int off = 1; off < 16; off <<= 1)                         \
                rs += __shfl_xor(rs, off, 64);                             \
            lrun[r] = lrun[r] * a + rs;                                    \
            _Pragma("unroll")                                              \
            for (int nd = 0; nd < 4; ++nd) oacc[nd][r] *= a;               \
        }                                                                  \
        /* P transpose via wave-private LDS (no barrier) */                \
        _Pragma("unroll")                                                  \
        for (int nf = 0; nf < 2; ++nf) {                                   \
            _Pragma("unroll")                                              \
            for (int r = 0; r < 4; ++r)                                    \
                s_p[4 * lg + r][32 * w + 16 * nf + lm] =                   \
                    (unsigned short)f2bf(p[nf][r]);                        \
        }                                                                  \
        asm volatile("s_waitcnt lgkmcnt(0)" ::: "memory");                 \
        const bf16x8 pa = *(const bf16x8*)&s_p[lm][32 * w + 8 * lg];       \
        /* O += P V (4 MFMA) */                                            \
        _Pragma("unroll")                                                  \
        for (int nd = 0; nd < 4; ++nd) {                                   \
            bf16x8 vb;                                                     \
            _Pragma("unroll")                                              \
            for (int j = 0; j < 8; ++j) vb[j] = f2bf(vf[nd][j]);           \
            oacc[nd] = __builtin_amdgcn_mfma_f32_16x16x32_bf16(            \
                pa, vb, oacc[nd], 0, 0, 0);                                \
        }                                                                  \
    }

    if (ntw > 0) {
        LOADBIAS(32 * w, btA, bgA)              // prologue: tile 0 bias
        for (int t = 0; t < ntw; t += 2) {
            BODY(t, btA, bgA, btB, bgB)
            if (t + 1 < ntw) BODY(t + 1, btB, bgB, btA, bgA)
        }
    }

    // ---- cross-wave combine (flash-decoding style, 4 partials) ----
    __syncthreads();   // everyone done with s_p; cmb/cml overlay it
    #pragma unroll
    for (int nd = 0; nd < 4; ++nd)
        #pragma unroll
        for (int r = 0; r < 4; ++r)
            cmb[(w * 16 + 4 * lg + r) * 68 + 16 * nd + lm] = oacc[nd][r];
    if (lm == 0) {
        #pragma unroll
        for (int r = 0; r < 4; ++r) {
            cml[w * 32 + 4 * lg + r]      = mrun[r];
            cml[w * 32 + 16 + 4 * lg + r] = lrun[r];
        }
    }
    __syncthreads();
    {
        const int q = tid >> 4, c = tid & 15;
        float mm[4], sc[4];
        float ms = -1e30f;
        #pragma unroll
        for (int i = 0; i < 4; ++i) { mm[i] = cml[i * 32 + q]; ms = fmaxf(ms, mm[i]); }
        float lt = 0.f;
        #pragma unroll
        for (int i = 0; i < 4; ++i) {
            sc[i] = __expf(mm[i] - ms);
            lt += cml[i * 32 + 16 + q] * sc[i];
        }
        const float inv = 1.f / lt;
        float4 acc = make_float4(0.f, 0.f, 0.f, 0.f);
        #pragma unroll
        for (int i = 0; i < 4; ++i) {
            const float4 v = *(const float4*)&cmb[(i * 16 + q) * 68 + 4 * c];
            acc.x += v.x * sc[i];  acc.y += v.y * sc[i];
            acc.z += v.z * sc[i];  acc.w += v.w * sc[i];
        }
        acc.x *= inv; acc.y *= inv; acc.z *= inv; acc.w *= inv;
        *(float4*)(out + ((size_t)(b * S_) + qb + q) * D_ + 4 * c) = acc;
    }
}

extern "C" void kernel_launch(void* const* d_in, const int* in_sizes, int n_in,
                              void* d_out, int out_size, void* d_ws, size_t ws_size,
                              hipStream_t stream) {
    const float* Q   = (const float*)d_in[0];
    const float* Kp  = (const float*)d_in[1];
    const float* V   = (const float*)d_in[2];
    const float* t_m = (const float*)d_in[3];
    const float* g_m = (const float*)d_in[4];
    // d_in[5] = mask, static tril -> causality hard-coded
    // batch-max pass eliminated: softmax shift-invariance (see kernel comment)

    attn_mfma_kernel<<<1024, 256, 0, stream>>>(Q, Kp, V, t_m, g_m,
                                               (float*)d_out);
}

// Round 11
// 34.238 us; speedup vs baseline: 1.6043x; 1.6043x over previous
//
#include <hip/hip_runtime.h>
#include <hip/hip_bf16.h>

#define B_  16
#define S_  1024
#define D_  64

typedef __attribute__((ext_vector_type(8))) short bf16x8;
typedef __attribute__((ext_vector_type(4))) float f32x4;

__device__ __forceinline__ unsigned short f2bf_u(float f) {
    __hip_bfloat16 h = __float2bfloat16(f);   // RTNE
    return __builtin_bit_cast(unsigned short, h);
}
__device__ __forceinline__ short f2bf(float f) {
    return (short)f2bf_u(f);
}
__device__ __forceinline__ unsigned pk2(float a, float b) {
    return (unsigned)f2bf_u(a) | ((unsigned)f2bf_u(b) << 16);
}

// Prep: K -> bf16 row-major (Kbf), V -> bf16 transposed [b][d][k] (VT).
// Blocks [0,512): Kbf (fully coalesced). Blocks [512,1024): VT
// (coalesced reads along d, 16B scattered writes - 2MB total, cheap).
__global__ __launch_bounds__(256) void prep_kernel(
    const float* __restrict__ K, const float* __restrict__ V,
    unsigned short* __restrict__ Kbf, unsigned short* __restrict__ VT)
{
    const int bid = blockIdx.x;
    if (bid < 512) {
        const size_t i = ((size_t)bid * 256 + threadIdx.x) * 8;
        const float4 x = *(const float4*)(K + i);
        const float4 y = *(const float4*)(K + i + 4);
        uint4 o = { pk2(x.x, x.y), pk2(x.z, x.w), pk2(y.x, y.y), pk2(y.z, y.w) };
        *(uint4*)(Kbf + i) = o;
    } else {
        const int i  = (bid - 512) * 256 + threadIdx.x;
        const int d  = i & 63;           // lane-varying -> coalesced reads
        const int kg = (i >> 6) & 127;
        const int b  = i >> 13;
        const float* vp = V + ((size_t)b * S_ + (size_t)kg * 8) * D_ + d;
        const float v0 = vp[0],   v1 = vp[64],  v2 = vp[128], v3 = vp[192];
        const float v4 = vp[256], v5 = vp[320], v6 = vp[384], v7 = vp[448];
        uint4 o = { pk2(v0, v1), pk2(v2, v3), pk2(v4, v5), pk2(v6, v7) };
        *(uint4*)(VT + ((size_t)b * D_ + d) * S_ + kg * 8) = o;
    }
}

// Fast path: bf16 MFMA flash attention with pre-converted K (bf16) and V^T
// (bf16, [b][d][k]). Per 32-k tile: K frag = 1 dwordx4 load, PV B-frag = 1
// contiguous dwordx4 load; zero per-tile f32->bf16 cvt for K/V.
// Algebra: |t_m - mx_t| = mx_t - t_m (mx is the batch max), so
// scores = QK/64 - t_m - g_m + const(b); softmax shift-invariant ->
// batch-max pass dropped. Causality (static tril mask) hard-coded.
// Block = (batch, 16-q tile), 256 thr = 4 waves; wave w owns k-strips
// {128t + 32w}; no barriers in main loop (s_p wave-private).
__global__ __launch_bounds__(256, 4) void attn_mfma_pre(
    const unsigned short* __restrict__ Kbf, const unsigned short* __restrict__ VT,
    const float* __restrict__ Q, const float* __restrict__ t_m,
    const float* __restrict__ g_m, float* __restrict__ out)
{
    __shared__ __align__(16) char smem[17920];
    unsigned short (*s_p)[136] = (unsigned short (*)[136])smem;  // [16][136] bf16
    float* cmb = (float*)smem;            // overlay post-loop: [4][16][68] f32
    float* cml = (float*)(smem + 17408);  // overlay post-loop: [4][2][16]  f32

    const int bid = blockIdx.x;
    const int b   = bid & 15;
    const int g   = bid >> 4;                            // [0,64)
    const int qt  = (g < 32) ? (63 - g) : (g - 32);      // balance heavy+light
    const int qb  = qt << 4;
    const int tid = threadIdx.x;
    const int w   = tid >> 6;      // wave 0..3 -> k-strip
    const int ln  = tid & 63;
    const int lg  = ln >> 4;       // lane group 0..3
    const int lm  = ln & 15;       // 0..15

    const size_t biasb = (size_t)b * S_ * S_;
    const float* tmb = t_m + biasb + (size_t)(qb + 4 * lg) * S_ + lm;
    const float* gmb = g_m + biasb + (size_t)(qb + 4 * lg) * S_ + lm;

    // K frag base: row (ke + 16nf + lm), col 32ks + 8lg
    const unsigned short* Kbb = Kbf + ((size_t)(b * S_) + lm) * D_ + 8 * lg;
    // V^T frag bases (static nd indexing): row d = 16nd + lm, col ke + 8lg
    const unsigned short* vt0 = VT + ((size_t)(b * D_) + 0  + lm) * S_ + 8 * lg;
    const unsigned short* vt1 = VT + ((size_t)(b * D_) + 16 + lm) * S_ + 8 * lg;
    const unsigned short* vt2 = VT + ((size_t)(b * D_) + 32 + lm) * S_ + 8 * lg;
    const unsigned short* vt3 = VT + ((size_t)(b * D_) + 48 + lm) * S_ + 8 * lg;

    // ---- persistent Q fragment: A[m=lm][d = 32ks + 8lg + j] ----
    bf16x8 qa[2];
    #pragma unroll
    for (int ks = 0; ks < 2; ++ks) {
        const float* qp = Q + ((size_t)(b * S_) + qb + lm) * D_ + 32 * ks + 8 * lg;
        const float4 x = *(const float4*)qp;
        const float4 y = *(const float4*)(qp + 4);
        bf16x8 f;
        f[0] = f2bf(x.x); f[1] = f2bf(x.y);
        f[2] = f2bf(x.z); f[3] = f2bf(x.w);
        f[4] = f2bf(y.x); f[5] = f2bf(y.y);
        f[6] = f2bf(y.z); f[7] = f2bf(y.w);
        qa[ks] = f;
    }

    float mrun[4] = {-1e30f, -1e30f, -1e30f, -1e30f};
    float lrun[4] = {0.f, 0.f, 0.f, 0.f};
    const f32x4 z4 = {0.f, 0.f, 0.f, 0.f};
    f32x4 oacc[4] = {z4, z4, z4, z4};

    // wave-private causal tile count: strips 128t + 32w that touch k <= qb+15
    const int ntw = ((qb + 15 - 32 * w) >> 7) + 1;   // <=0 when strip beyond diag

    for (int t = 0; t < ntw; ++t) {
        const int ke = (t << 7) + 32 * w;   // this wave's strip base

        // ---- K fragments: 4x dwordx4 (L2-hot, base + imm offsets) ----
        const bf16x8* kp = (const bf16x8*)(Kbb + (size_t)ke * D_);
        bf16x8 kf00 = kp[0];                                   // nf=0 ks=0
        bf16x8 kf01 = *(const bf16x8*)((const unsigned short*)kp + 32);
        bf16x8 kf10 = *(const bf16x8*)((const unsigned short*)kp + 16 * D_);
        bf16x8 kf11 = *(const bf16x8*)((const unsigned short*)kp + 16 * D_ + 32);

        // ---- V^T fragments: 4x dwordx4, contiguous in k ----
        const bf16x8 vb0 = *(const bf16x8*)(vt0 + ke);
        const bf16x8 vb1 = *(const bf16x8*)(vt1 + ke);
        const bf16x8 vb2 = *(const bf16x8*)(vt2 + ke);
        const bf16x8 vb3 = *(const bf16x8*)(vt3 + ke);

        // ---- bias loads (issue early; cold triangle stream) ----
        float bt[2][4], bg[2][4];
        #pragma unroll
        for (int nf = 0; nf < 2; ++nf)
            #pragma unroll
            for (int r = 0; r < 4; ++r) {
                const size_t off = (size_t)r * S_ + ke + 16 * nf;
                bt[nf][r] = tmb[off];
                bg[nf][r] = gmb[off];
            }

        // ---- S = Q K^T (4 MFMA) ----
        f32x4 sa[2] = {z4, z4};
        sa[0] = __builtin_amdgcn_mfma_f32_16x16x32_bf16(qa[0], kf00, sa[0], 0, 0, 0);
        sa[0] = __builtin_amdgcn_mfma_f32_16x16x32_bf16(qa[1], kf01, sa[0], 0, 0, 0);
        sa[1] = __builtin_amdgcn_mfma_f32_16x16x32_bf16(qa[0], kf10, sa[1], 0, 0, 0);
        sa[1] = __builtin_amdgcn_mfma_f32_16x16x32_bf16(qa[1], kf11, sa[1], 0, 0, 0);

        // ---- scores: QK/64 - t_m - g_m (constant shift dropped) + causal ----
        float p[2][4], tmax[4];
        #pragma unroll
        for (int r = 0; r < 4; ++r) {
            const int qg = qb + 4 * lg + r;
            float s0 = sa[0][r] * (1.f / 64.f) - bt[0][r] - bg[0][r];
            float s1 = sa[1][r] * (1.f / 64.f) - bt[1][r] - bg[1][r];
            if (ke + lm > qg)      s0 = -1e30f;
            if (ke + 16 + lm > qg) s1 = -1e30f;
            p[0][r] = s0;  p[1][r] = s1;
            tmax[r] = fmaxf(s0, s1);
        }
        #pragma unroll
        for (int off = 1; off < 16; off <<= 1)
            #pragma unroll
            for (int r = 0; r < 4; ++r)
                tmax[r] = fmaxf(tmax[r], __shfl_xor(tmax[r], off, 64));

        #pragma unroll
        for (int r = 0; r < 4; ++r) {
            const float mn = fmaxf(mrun[r], tmax[r]);
            const float a  = __expf(mrun[r] - mn);
            mrun[r] = mn;
            const float p0 = __expf(p[0][r] - mn);
            const float p1 = __expf(p[1][r] - mn);
            p[0][r] = p0;  p[1][r] = p1;
            float rs = p0 + p1;
            #pragma unroll
            for (int off = 1; off < 16; off <<= 1)
                rs += __shfl_xor(rs, off, 64);
            lrun[r] = lrun[r] * a + rs;
            #pragma unroll
            for (int nd = 0; nd < 4; ++nd) oacc[nd][r] *= a;
        }

        // ---- P transpose via wave-private LDS (no barrier) ----
        #pragma unroll
        for (int nf = 0; nf < 2; ++nf)
            #pragma unroll
            for (int r = 0; r < 4; ++r)
                s_p[4 * lg + r][32 * w + 16 * nf + lm] = f2bf_u(p[nf][r]);
        asm volatile("s_waitcnt lgkmcnt(0)" ::: "memory");
        const bf16x8 pa = *(const bf16x8*)&s_p[lm][32 * w + 8 * lg];

        // ---- O += P V (4 MFMA, B-frags preloaded) ----
        oacc[0] = __builtin_amdgcn_mfma_f32_16x16x32_bf16(pa, vb0, oacc[0], 0, 0, 0);
        oacc[1] = __builtin_amdgcn_mfma_f32_16x16x32_bf16(pa, vb1, oacc[1], 0, 0, 0);
        oacc[2] = __builtin_amdgcn_mfma_f32_16x16x32_bf16(pa, vb2, oacc[2], 0, 0, 0);
        oacc[3] = __builtin_amdgcn_mfma_f32_16x16x32_bf16(pa, vb3, oacc[3], 0, 0, 0);
    }

    // ---- cross-wave combine (flash-decoding style, 4 partials) ----
    __syncthreads();   // everyone done with s_p; cmb/cml overlay it
    #pragma unroll
    for (int nd = 0; nd < 4; ++nd)
        #pragma unroll
        for (int r = 0; r < 4; ++r)
            cmb[(w * 16 + 4 * lg + r) * 68 + 16 * nd + lm] = oacc[nd][r];
    if (lm == 0) {
        #pragma unroll
        for (int r = 0; r < 4; ++r) {
            cml[w * 32 + 4 * lg + r]      = mrun[r];
            cml[w * 32 + 16 + 4 * lg + r] = lrun[r];
        }
    }
    __syncthreads();
    {
        const int q = tid >> 4, c = tid & 15;
        float mm[4], sc[4];
        float ms = -1e30f;
        #pragma unroll
        for (int i = 0; i < 4; ++i) { mm[i] = cml[i * 32 + q]; ms = fmaxf(ms, mm[i]); }
        float lt = 0.f;
        #pragma unroll
        for (int i = 0; i < 4; ++i) {
            sc[i] = __expf(mm[i] - ms);
            lt += cml[i * 32 + 16 + q] * sc[i];
        }
        const float inv = 1.f / lt;
        float4 acc = make_float4(0.f, 0.f, 0.f, 0.f);
        #pragma unroll
        for (int i = 0; i < 4; ++i) {
            const float4 v = *(const float4*)&cmb[(i * 16 + q) * 68 + 4 * c];
            acc.x += v.x * sc[i];  acc.y += v.y * sc[i];
            acc.z += v.z * sc[i];  acc.w += v.w * sc[i];
        }
        acc.x *= inv; acc.y *= inv; acc.z *= inv; acc.w *= inv;
        *(float4*)(out + ((size_t)(b * S_) + qb + q) * D_ + 4 * c) = acc;
    }
}

// Fallback (ws too small): verbatim R7 kernel - f32 K/V direct from L2/L3.
__global__ __launch_bounds__(256, 4) void attn_mfma_kernel(
    const float* __restrict__ Q, const float* __restrict__ K,
    const float* __restrict__ V, const float* __restrict__ t_m,
    const float* __restrict__ g_m, float* __restrict__ out)
{
    __shared__ __align__(16) char smem[17920];
    unsigned short (*s_p)[136] = (unsigned short (*)[136])smem;
    float* cmb = (float*)smem;
    float* cml = (float*)(smem + 17408);

    const int bid = blockIdx.x;
    const int b   = bid & 15;
    const int g   = bid >> 4;
    const int qt  = (g < 32) ? (63 - g) : (g - 32);
    const int qb  = qt << 4;
    const int tid = threadIdx.x;
    const int w   = tid >> 6;
    const int ln  = tid & 63;
    const int lg  = ln >> 4;
    const int lm  = ln & 15;

    const size_t kvb   = (size_t)(b * S_) * D_;
    const size_t biasb = (size_t)b * S_ * S_;
    const float* Kb = K + kvb;
    const float* Vb = V + kvb;

    bf16x8 qa[2];
    #pragma unroll
    for (int ks = 0; ks < 2; ++ks) {
        const float* qp = Q + ((size_t)(b * S_) + qb + lm) * D_ + 32 * ks + 8 * lg;
        const float4 x = *(const float4*)qp;
        const float4 y = *(const float4*)(qp + 4);
        bf16x8 f;
        f[0] = f2bf(x.x); f[1] = f2bf(x.y);
        f[2] = f2bf(x.z); f[3] = f2bf(x.w);
        f[4] = f2bf(y.x); f[5] = f2bf(y.y);
        f[6] = f2bf(y.z); f[7] = f2bf(y.w);
        qa[ks] = f;
    }

    float mrun[4] = {-1e30f, -1e30f, -1e30f, -1e30f};
    float lrun[4] = {0.f, 0.f, 0.f, 0.f};
    const f32x4 z4 = {0.f, 0.f, 0.f, 0.f};
    f32x4 oacc[4] = {z4, z4, z4, z4};

    const int ntw = ((qb + 15 - 32 * w) >> 7) + 1;

    for (int t = 0; t < ntw; ++t) {
        const int ke = (t << 7) + 32 * w;

        bf16x8 kf[2][2];
        #pragma unroll
        for (int nf = 0; nf < 2; ++nf)
            #pragma unroll
            for (int ks = 0; ks < 2; ++ks) {
                const float* kp = Kb + (size_t)(ke + 16 * nf + lm) * D_ + 32 * ks + 8 * lg;
                const float4 x = *(const float4*)kp;
                const float4 y = *(const float4*)(kp + 4);
                bf16x8 f;
                f[0] = f2bf(x.x); f[1] = f2bf(x.y);
                f[2] = f2bf(x.z); f[3] = f2bf(x.w);
                f[4] = f2bf(y.x); f[5] = f2bf(y.y);
                f[6] = f2bf(y.z); f[7] = f2bf(y.w);
                kf[nf][ks] = f;
            }

        float bt[2][4], bg[2][4];
        #pragma unroll
        for (int nf = 0; nf < 2; ++nf)
            #pragma unroll
            for (int r = 0; r < 4; ++r) {
                const size_t off = biasb + (size_t)(qb + 4 * lg + r) * S_
                                 + ke + 16 * nf + lm;
                bt[nf][r] = t_m[off];
                bg[nf][r] = g_m[off];
            }

        f32x4 sa[2] = {z4, z4};
        #pragma unroll
        for (int nf = 0; nf < 2; ++nf)
            #pragma unroll
            for (int ks = 0; ks < 2; ++ks)
                sa[nf] = __builtin_amdgcn_mfma_f32_16x16x32_bf16(
                    qa[ks], kf[nf][ks], sa[nf], 0, 0, 0);

        float vf[4][8];
        #pragma unroll
        for (int nd = 0; nd < 4; ++nd)
            #pragma unroll
            for (int j = 0; j < 8; ++j)
                vf[nd][j] = Vb[(size_t)(ke + 8 * lg + j) * D_ + 16 * nd + lm];

        float p[2][4], tmax[4];
        #pragma unroll
        for (int r = 0; r < 4; ++r) {
            const int qg = qb + 4 * lg + r;
            float s0 = sa[0][r] * (1.f / 64.f) - bt[0][r] - bg[0][r];
            float s1 = sa[1][r] * (1.f / 64.f) - bt[1][r] - bg[1][r];
            if (ke + lm > qg)      s0 = -1e30f;
            if (ke + 16 + lm > qg) s1 = -1e30f;
            p[0][r] = s0;  p[1][r] = s1;
            tmax[r] = fmaxf(s0, s1);
        }
        #pragma unroll
        for (int off = 1; off < 16; off <<= 1)
            #pragma unroll
            for (int r = 0; r < 4; ++r)
                tmax[r] = fmaxf(tmax[r], __shfl_xor(tmax[r], off, 64));

        #pragma unroll
        for (int r = 0; r < 4; ++r) {
            const float mn = fmaxf(mrun[r], tmax[r]);
            const float a  = __expf(mrun[r] - mn);
            mrun[r] = mn;
            const float p0 = __expf(p[0][r] - mn);
            const float p1 = __expf(p[1][r] - mn);
            p[0][r] = p0;  p[1][r] = p1;
            float rs = p0 + p1;
            #pragma unroll
            for (int off = 1; off < 16; off <<= 1)
                rs += __shfl_xor(rs, off, 64);
            lrun[r] = lrun[r] * a + rs;
            #pragma unroll
            for (int nd = 0; nd < 4; ++nd) oacc[nd][r] *= a;
        }

        #pragma unroll
        for (int nf = 0; nf < 2; ++nf)
            #pragma unroll
            for (int r = 0; r < 4; ++r)
                s_p[4 * lg + r][32 * w + 16 * nf + lm] = f2bf_u(p[nf][r]);
        asm volatile("s_waitcnt lgkmcnt(0)" ::: "memory");
        const bf16x8 pa = *(const bf16x8*)&s_p[lm][32 * w + 8 * lg];

        #pragma unroll
        for (int nd = 0; nd < 4; ++nd) {
            bf16x8 vb;
            #pragma unroll
            for (int j = 0; j < 8; ++j) vb[j] = f2bf(vf[nd][j]);
            oacc[nd] = __builtin_amdgcn_mfma_f32_16x16x32_bf16(
                pa, vb, oacc[nd], 0, 0, 0);
        }
    }

    __syncthreads();
    #pragma unroll
    for (int nd = 0; nd < 4; ++nd)
        #pragma unroll
        for (int r = 0; r < 4; ++r)
            cmb[(w * 16 + 4 * lg + r) * 68 + 16 * nd + lm] = oacc[nd][r];
    if (lm == 0) {
        #pragma unroll
        for (int r = 0; r < 4; ++r) {
            cml[w * 32 + 4 * lg + r]      = mrun[r];
            cml[w * 32 + 16 + 4 * lg + r] = lrun[r];
        }
    }
    __syncthreads();
    {
        const int q = tid >> 4, c = tid & 15;
        float mm[4], sc[4];
        float ms = -1e30f;
        #pragma unroll
        for (int i = 0; i < 4; ++i) { mm[i] = cml[i * 32 + q]; ms = fmaxf(ms, mm[i]); }
        float lt = 0.f;
        #pragma unroll
        for (int i = 0; i < 4; ++i) {
            sc[i] = __expf(mm[i] - ms);
            lt += cml[i * 32 + 16 + q] * sc[i];
        }
        const float inv = 1.f / lt;
        float4 acc = make_float4(0.f, 0.f, 0.f, 0.f);
        #pragma unroll
        for (int i = 0; i < 4; ++i) {
            const float4 v = *(const float4*)&cmb[(i * 16 + q) * 68 + 4 * c];
            acc.x += v.x * sc[i];  acc.y += v.y * sc[i];
            acc.z += v.z * sc[i];  acc.w += v.w * sc[i];
        }
        acc.x *= inv; acc.y *= inv; acc.z *= inv; acc.w *= inv;
        *(float4*)(out + ((size_t)(b * S_) + qb + q) * D_ + 4 * c) = acc;
    }
}

extern "C" void kernel_launch(void* const* d_in, const int* in_sizes, int n_in,
                              void* d_out, int out_size, void* d_ws, size_t ws_size,
                              hipStream_t stream) {
    const float* Q   = (const float*)d_in[0];
    const float* Kp  = (const float*)d_in[1];
    const float* V   = (const float*)d_in[2];
    const float* t_m = (const float*)d_in[3];
    const float* g_m = (const float*)d_in[4];
    // d_in[5] = mask, static tril -> causality hard-coded
    // batch-max pass eliminated: softmax shift-invariance

    const size_t need = (size_t)2 * B_ * S_ * D_ * sizeof(unsigned short); // 4 MiB
    if (ws_size >= need) {
        unsigned short* Kbf = (unsigned short*)d_ws;
        unsigned short* VT  = Kbf + (size_t)B_ * S_ * D_;
        prep_kernel<<<1024, 256, 0, stream>>>(Kp, V, Kbf, VT);
        attn_mfma_pre<<<1024, 256, 0, stream>>>(Kbf, VT, Q, t_m, g_m,
                                                (float*)d_out);
    } else {
        attn_mfma_kernel<<<1024, 256, 0, stream>>>(Q, Kp, V, t_m, g_m,
                                                   (float*)d_out);
    }
}